// Round 15
// baseline (204.518 us; speedup 1.0000x reference)
//
#include <hip/hip_runtime.h>

// Problem constants (fixed by the reference).
#define D      256        // vq_embed_dim == C
#define N_E    16384      // codebook size
#define NPTS   8192       // B*H*W
#define ZOUT   2097152    // elements of z_hat_out
#define MARGIN 2.0e-2f    // candidate window; bf16-hi GEMM d-error ~7 sigma
#define STRIPS 8          // 512-code strips per block
#define ECH    17         // Epk chunks per group: 16 K-chunks + 1 e2-fold chunk

typedef short bf16x8 __attribute__((ext_vector_type(8)));
typedef unsigned short us8 __attribute__((ext_vector_type(8)));
typedef float f32x16 __attribute__((ext_vector_type(16)));
typedef unsigned long long u64;

__device__ __forceinline__ unsigned short f2bf(float x) {  // RNE
    unsigned int u = __float_as_uint(x);
    return (unsigned short)((u + 0x7FFFu + ((u >> 16) & 1u)) >> 16);
}
__device__ __forceinline__ float bf2f(unsigned short h) {
    return __uint_as_float((unsigned int)h << 16);
}
__device__ __forceinline__ void gl_lds16(const void* g, void* l) {
    __builtin_amdgcn_global_load_lds(
        (const __attribute__((address_space(1))) unsigned int*)g,
        (__attribute__((address_space(3))) unsigned int*)l, 16, 0, 0);
}

// ---------------------------------------------------------------------------
// Fused prep (r13 proven, unchanged). Blocks [0,256): z -> Zpk = bf16(-2z),
// 16 fragment chunks/group. Blocks [256,768): emb -> Epk = bf16(emb), ECH=17
// chunks/group (chunk 16 = e2 hi/lo A-fragment for the GEMM's e2 fold).
// e2 fp32 for rescore. Zeroes loss.
// ---------------------------------------------------------------------------
__global__ __launch_bounds__(256) void prep(
    const float* __restrict__ z, const float* __restrict__ emb,
    unsigned short* __restrict__ Zpk, unsigned short* __restrict__ Epk,
    float* __restrict__ e2, float* __restrict__ loss) {
    __shared__ float sh[32];
    const int t = threadIdx.x;
    if (blockIdx.x == 0 && t == 0) loss[0] = 0.f;
    if (blockIdx.x < 256) {
        const int n0 = blockIdx.x * 32;
        const int p = t & 31, ks8 = t >> 5;     // 8 k-slabs of 32
        const int n = n0 + p;
        const int b = n >> 10, hw = n & 1023;
        const float* zb = z + (size_t)b * 262144 + hw;
        const int k0 = ks8 * 32;
        float v[32];
        #pragma unroll
        for (int kk = 0; kk < 32; ++kk)
            v[kk] = zb[(size_t)(k0 + kk) * 1024];   // coalesced in p
        const int g = n >> 5;
        #pragma unroll
        for (int i = 0; i < 4; ++i) {               // 4 us8 per 32-k slab
            us8 hv;
            #pragma unroll
            for (int c = 0; c < 8; ++c) hv[c] = f2bf(-2.0f * v[i * 8 + c]);
            const int kabs = k0 + i * 8;
            const int ks = kabs >> 4;
            const int l = (n & 31) + ((kabs >> 3) & 1) * 32;
            *(us8*)(Zpk + ((size_t)(g * 16 + ks) * 64 + l) * 8) = hv;
        }
    } else {
        const int bi = blockIdx.x - 256;            // code group id
        const int j0 = bi * 32;
        const int jj = j0 + (t >> 3), q = t & 7;    // 8 k-slabs of 32
        const float* row = emb + (size_t)jj * D + q * 32;
        float v[32];
        float s = 0.f;
        #pragma unroll
        for (int i = 0; i < 8; ++i) {
            const float4 x = *(const float4*)(row + i * 4);
            v[i * 4] = x.x; v[i * 4 + 1] = x.y; v[i * 4 + 2] = x.z; v[i * 4 + 3] = x.w;
            s += x.x * x.x + x.y * x.y + x.z * x.z + x.w * x.w;
        }
        #pragma unroll
        for (int i = 0; i < 4; ++i) {
            us8 hv;
            #pragma unroll
            for (int c = 0; c < 8; ++c) hv[c] = f2bf(v[i * 8 + c]);
            const int kabs = q * 32 + i * 8;
            const int ks = kabs >> 4;
            const int l = (jj & 31) + ((kabs >> 3) & 1) * 32;
            *(us8*)(Epk + ((size_t)(bi * ECH + ks) * 64 + l) * 8) = hv;
        }
        s += __shfl_xor(s, 1);
        s += __shfl_xor(s, 2);
        s += __shfl_xor(s, 4);
        if (q == 0) { e2[jj] = s; sh[t >> 3] = s; }
        __syncthreads();
        if (t < 64) {   // chunk 16: lane l<32 -> {e2_hi, e2_lo, 0..}; else 0
            us8 hv;
            #pragma unroll
            for (int c = 0; c < 8; ++c) hv[c] = 0;
            if (t < 32) {
                const float vv = sh[t];
                const unsigned short hi = f2bf(vv);
                hv[0] = hi;
                hv[1] = f2bf(vv - bf2f(hi));
            }
            *(us8*)(Epk + ((size_t)bi * ECH + 16) * 512 + t * 8) = hv;
        }
    }
}

// ---------------------------------------------------------------------------
// GEMM + group-min + candidate mask. 4-WAVES-PER-SIMD restructure.
// Corrected arithmetic: one 32x32x16 MFMA = 32 cy PER SIMD (8 cy was the
// per-CU figure). r13's 2 waves/SIMD x 136 MFMA x 32 cy = 8.7K cy of matrix
// work vs 24.6K cy strip wall = 35% — matching MfmaUtil. The other 65% is
// VALU+stalls with too little TLP. Failure matrix: r9 (1 w/SIMD: no TLP),
// r10 (2 w/SIMD: E-stream wall), r11 (barriers serialize 1 block/CU).
// Untried corner — ALL of: small acc (64 AGPR) -> 4 waves/SIMD; zero
// barriers after staging (waves drift; epilogues overlap other waves'
// MFMAs); E-traffic unchanged (64 point-tiles x 8.9 MB, L2-resident per
// r13's grid orientation).
//   wave  = 128 codes x 32 points, acc[4] (64 AGPR), depth-1 E ring; the
//           ring's last prefetch (chunk 16) IS the e2-fold fragment.
//   block = 16 waves (1024 thr) = 4 code-cols x 4 point-groups; 128 points
//           (Zbuf 64 KB); 512 codes/strip; STRIPS=8.
//   grid  = (4, 64) = 256 blocks = 1 block/CU, exactly one generation.
// Per CU-k-step: LDS 16 reads x 12 = 192 cy << matrix 512 cy; E ~64 B/cy
// with 4-way intra-block L1 sharing per code-col.
// d~ = acc directly. Per (point, 64-code group): tminv[pt][g] min,
// tmask[pt][g] margin bits (layout/math byte-identical to r13).
// Tripwires: dur > 85 us or FETCH > 40 MB (spill past the 128-VGPR cap)
// => revert to r13 gemm and declare the 2-wave ceiling final.
// ---------------------------------------------------------------------------
__global__ __launch_bounds__(1024) void mfma_gemm(
    const unsigned short* __restrict__ Epk, const unsigned short* __restrict__ Zpk,
    float* __restrict__ tminv, u64* __restrict__ tmask) {
    __shared__ unsigned short Zbuf[64 * 512];   // 64 KB (128 points)

    const int tid = threadIdx.x, lane = tid & 63, wid = tid >> 6;  // 16 waves
    const int c32 = lane & 31, l5 = lane >> 5;
    const int cc = wid & 3, pg = wid >> 2;      // code-col, point-group
    const int n0 = (int)blockIdx.y * 128;             // point tile (64)
    const int cs0 = (int)blockIdx.x * (STRIPS * 512); // code strip-col (4)

    // Ones B-fragment for the e2 fold: k-slots 0,1 = 1.0 (l5==0 lanes).
    us8 puu;
    #pragma unroll
    for (int c = 0; c < 8; ++c) puu[c] = 0;
    if (l5 == 0) { puu[0] = 0x3F80; puu[1] = 0x3F80; }
    const bf16x8 pu = (bf16x8)puu;

    // Stage 128 points = 4 groups x 16 chunks = 64 chunks; wave stages 4.
    #pragma unroll
    for (int i = 0; i < 4; ++i) {
        const int ch = wid * 4 + i;             // 0..63
        gl_lds16(Zpk + ((size_t)((n0 >> 5) + (ch >> 4)) * 16 + (ch & 15)) * 512
                     + lane * 8,
                 Zbuf + ch * 512);
    }
    __syncthreads();   // the ONLY barrier

    const unsigned short* zb = Zbuf + (pg * 16) * 512 + lane * 8;

    for (int s = 0; s < STRIPS; ++s) {
        const int cb = cs0 + s * 512 + cc * 128;   // this wave's 128 codes
        const unsigned short* eb =
            Epk + ((size_t)(cb >> 5) * ECH) * 512 + lane * 8;  // 4 Epk groups

        f32x16 acc[4];
        const f32x16 z16 = {0.f};
        #pragma unroll
        for (int f = 0; f < 4; ++f) acc[f] = z16;

        // Depth-1 E prefetch ring over 4 code-fragments; chunk ks+1 runs
        // 0..16 — the final prefetch (chunk 16) is the e2-fold fragment.
        bf16x8 ec[4], en[4];
        #pragma unroll
        for (int f = 0; f < 4; ++f)
            ec[f] = *(const bf16x8*)(eb + (f * ECH + 0) * 512);
        bf16x8 pc = *(const bf16x8*)(zb);
        bf16x8 pn;

        #pragma unroll 4
        for (int ks = 0; ks < 16; ++ks) {
            #pragma unroll
            for (int f = 0; f < 4; ++f)
                en[f] = *(const bf16x8*)(eb + (f * ECH + ks + 1) * 512);
            if (ks < 15) pn = *(const bf16x8*)(zb + (ks + 1) * 512);
            acc[0] = __builtin_amdgcn_mfma_f32_32x32x16_bf16(ec[0], pc, acc[0], 0, 0, 0);
            acc[1] = __builtin_amdgcn_mfma_f32_32x32x16_bf16(ec[1], pc, acc[1], 0, 0, 0);
            acc[2] = __builtin_amdgcn_mfma_f32_32x32x16_bf16(ec[2], pc, acc[2], 0, 0, 0);
            acc[3] = __builtin_amdgcn_mfma_f32_32x32x16_bf16(ec[3], pc, acc[3], 0, 0, 0);
            #pragma unroll
            for (int f = 0; f < 4; ++f) ec[f] = en[f];
            if (ks < 15) pc = pn;
        }
        // e2 fold: chunk 16 of each group is now in ec. acc becomes d~.
        #pragma unroll
        for (int f = 0; f < 4; ++f)
            acc[f] = __builtin_amdgcn_mfma_f32_32x32x16_bf16(ec[f], pu, acc[f], 0, 0, 0);

        // Epilogue: per point-lane, per 64-code group (frag pair 2gi,2gi+1):
        // min over 64 codes + candidate bitmask (r13 math verbatim).
        #pragma unroll
        for (int gi = 0; gi < 2; ++gi) {
            float m = acc[2 * gi][0];
            #pragma unroll
            for (int r = 1; r < 16; ++r) m = fminf(m, acc[2 * gi][r]);
            #pragma unroll
            for (int r = 0; r < 16; ++r) m = fminf(m, acc[2 * gi + 1][r]);
            m = fminf(m, __shfl_xor(m, 32));   // fold the two l5 halves
            const float th = m + MARGIN;
            unsigned mk[2];
            #pragma unroll
            for (int i = 0; i < 2; ++i) {
                unsigned mm = 0;
                #pragma unroll
                for (int r = 0; r < 16; ++r) {
                    const int row = (r & 3) + 8 * (r >> 2) + 4 * l5;
                    mm |= (acc[2 * gi + i][r] <= th) ? (1u << row) : 0u;
                }
                mk[i] = mm | (unsigned)__shfl_xor((int)mm, 32);
            }
            if (l5 == 0) {
                const size_t pt = (size_t)(n0 + pg * 32 + c32);
                const int g = (cb >> 6) + gi;
                tminv[pt * 256 + g] = m;
                tmask[pt * 256 + g] = ((u64)mk[1] << 32) | (u64)mk[0];
            }
        }
    }
}

// ---------------------------------------------------------------------------
// Fused rescore + quantize/loss (r13 proven, unchanged). 256 blocks x 1024
// thr; block = 32 consecutive points. z tile staged once into LDS
// smz[32][257] serving phase-1 z-rows and phase-2 zv.
// ---------------------------------------------------------------------------
__global__ __launch_bounds__(1024) void rescore_quant(
    const float* __restrict__ tminv, const u64* __restrict__ tmask,
    const float* __restrict__ emb, const float* __restrict__ e2,
    const float* __restrict__ z, float* __restrict__ out,
    float* __restrict__ out_idx, float* __restrict__ loss) {
    __shared__ float smz[32][257];   // [pt][ch], pad 257
    __shared__ int idx_s[32];
    __shared__ float wsum[16];
    const int tid = threadIdx.x, lane = tid & 63, wd = tid >> 6;
    const int n0 = blockIdx.x * 32;
    const int b = n0 >> 10, hw0 = n0 & 1023;

    // ---- stage z tile: coalesced 128B lines, conflict-free LDS writes ----
    #pragma unroll
    for (int pass = 0; pass < 8; ++pass) {
        const int c = pass * 32 + (tid >> 5);
        const int hw = tid & 31;
        smz[hw][c] = z[(size_t)b * 262144 + (size_t)c * 1024 + hw0 + hw];
    }
    __syncthreads();

    // ---- Phase 1: rescore (each wave: 2 points serially) ----
    #pragma unroll 1
    for (int p = 0; p < 2; ++p) {
        const int lp = wd * 2 + p;
        const int n = n0 + lp;
        const float* zrow = smz[lp];
        const float4 zr = {zrow[lane * 4], zrow[lane * 4 + 1],
                           zrow[lane * 4 + 2], zrow[lane * 4 + 3]};
        const float4 tv = *(const float4*)(tminv + (size_t)n * 256 + lane * 4);

        float m1 = fminf(fminf(tv.x, tv.y), fminf(tv.z, tv.w));
        #pragma unroll
        for (int st = 1; st < 64; st <<= 1) m1 = fminf(m1, __shfl_xor(m1, st));
        const float thresh = m1 + MARGIN;

        u64 best = ~0ull;
        const float tva[4] = {tv.x, tv.y, tv.z, tv.w};
        #pragma unroll
        for (int k = 0; k < 4; ++k) {
            u64 gm = __ballot(tva[k] <= thresh);
            while (gm) {
                const int bit = (int)__builtin_ctzll(gm);
                gm &= gm - 1;
                const int g = bit * 4 + k;                 // 64-code group id
                u64 cm = tmask[(size_t)n * 256 + g];       // uniform broadcast
                while (cm) {
                    const int r = (int)__builtin_ctzll(cm);
                    cm &= cm - 1;
                    const int c = g * 64 + r;
                    const float4 ev = *(const float4*)(emb + (size_t)c * D + lane * 4);
                    float s = zr.x * ev.x + zr.y * ev.y + zr.z * ev.z + zr.w * ev.w;
                    #pragma unroll
                    for (int st = 1; st < 64; st <<= 1) s += __shfl_xor(s, st);
                    const float d = e2[c] - 2.0f * s;
                    unsigned int u = __float_as_uint(d);
                    u = (u & 0x80000000u) ? ~u : (u | 0x80000000u);
                    const u64 key = ((u64)u << 32) | (unsigned int)c;
                    if (key < best) best = key;            // same on all lanes
                }
            }
        }
        if (lane == 0)
            idx_s[lp] = (int)(unsigned int)(best & 0xFFFFFFFFull);
    }
    __syncthreads();

    // ---- Phase 2: gather + z_hat_out + loss (+ coalesced out_idx) ----
    if (tid < 32) {
        const float fv = (float)idx_s[tid];
        #pragma unroll
        for (int sc = 0; sc < 4; ++sc)
            out_idx[b * 4096 + sc * 1024 + hw0 + tid] = fv;
    }
    const int hw_l = tid & 31, cg = tid >> 5;   // cg in [0,32), 8 c each
    const int j = idx_s[hw_l];
    const float* er = emb + (size_t)j * D + cg * 8;
    const float4 q0 = *(const float4*)er;
    const float4 q1 = *(const float4*)(er + 4);
    const float qv[8] = {q0.x, q0.y, q0.z, q0.w, q1.x, q1.y, q1.z, q1.w};
    float e = 0.f;
    #pragma unroll
    for (int cc = 0; cc < 8; ++cc) {
        const int c = cg * 8 + cc;
        const size_t zi = (size_t)b * 262144 + (size_t)c * 1024 + hw0 + hw_l;
        const float zv = smz[hw_l][c];
        const float q = qv[cc];
        const float zh = ((q + q) + q) + q;   // mimic 4-step accumulation
        out[zi] = zv + (zh - zv);
        e += 30.0f * q * q - 20.0f * q * zv + 4.0f * zv * zv;
    }
    #pragma unroll
    for (int off = 32; off > 0; off >>= 1) e += __shfl_down(e, off);
    if (lane == 0) wsum[wd] = e;
    __syncthreads();
    if (tid == 0) {
        float s = 0.f;
        #pragma unroll
        for (int i = 0; i < 16; ++i) s += wsum[i];
        atomicAdd(loss, s * (0.3125f / 2097152.0f));
    }
}

// ---------------------------------------------------------------------------
extern "C" void kernel_launch(void* const* d_in, const int* in_sizes, int n_in,
                              void* d_out, int out_size, void* d_ws, size_t ws_size,
                              hipStream_t stream) {
    const float* z = (const float*)d_in[0];     // [8,256,32,32]
    const float* emb = (const float*)d_in[1];   // [16384,256]
    float* out = (float*)d_out;                 // z_hat_out | loss | total_idx

    // Workspace (~37 MB)
    unsigned short* Zpk = (unsigned short*)d_ws;            // 8192*256 bf16
    unsigned short* Epk = Zpk + (size_t)NPTS * D;           // 512 groups * 17 * 512
    float* e2 = (float*)(Epk + (size_t)(N_E / 32) * ECH * 512);  // 16384 f32
    float* tminv = e2 + N_E;                                // 8192*256 f32 [pt][g]
    u64* tmask = (u64*)(tminv + (size_t)NPTS * 256);        // 8192*256 u64 [pt][g]

    float* loss = out + ZOUT;
    float* out_idx = out + ZOUT + 1;

    prep<<<768, 256, 0, stream>>>(z, emb, Zpk, Epk, e2, loss);
    mfma_gemm<<<dim3(N_E / (STRIPS * 512), NPTS / 128), 1024, 0, stream>>>(
        Epk, Zpk, tminv, tmask);
    rescore_quant<<<256, 1024, 0, stream>>>(tminv, tmask, emb, e2, z,
                                            out, out_idx, loss);
}

// Round 16
// 158.587 us; speedup vs baseline: 1.2896x; 1.2896x over previous
//
#include <hip/hip_runtime.h>

// Problem constants (fixed by the reference).
#define D      256        // vq_embed_dim == C
#define N_E    16384      // codebook size
#define NPTS   8192       // B*H*W
#define ZOUT   2097152    // elements of z_hat_out
#define MARGIN 2.0e-2f    // candidate window; bf16-hi GEMM d-error ~7 sigma
#define STRIPS 4          // 256-code strips per block
#define ECH    17         // Epk chunks per group: 16 K-chunks + 1 e2-fold chunk

typedef short bf16x8 __attribute__((ext_vector_type(8)));
typedef unsigned short us8 __attribute__((ext_vector_type(8)));
typedef float f32x16 __attribute__((ext_vector_type(16)));
typedef unsigned long long u64;

__device__ __forceinline__ unsigned short f2bf(float x) {  // RNE
    unsigned int u = __float_as_uint(x);
    return (unsigned short)((u + 0x7FFFu + ((u >> 16) & 1u)) >> 16);
}
__device__ __forceinline__ float bf2f(unsigned short h) {
    return __uint_as_float((unsigned int)h << 16);
}
__device__ __forceinline__ void gl_lds16(const void* g, void* l) {
    __builtin_amdgcn_global_load_lds(
        (const __attribute__((address_space(1))) unsigned int*)g,
        (__attribute__((address_space(3))) unsigned int*)l, 16, 0, 0);
}

// ---------------------------------------------------------------------------
// Fused prep. Blocks [0,256): z -> Zpk = bf16(-2z), 16 fragment chunks/group.
// Blocks [256,768): emb -> Epk = bf16(emb), ECH=17 chunks/group (chunk 16 =
// e2 hi/lo A-fragment for the GEMM's e2 fold). e2 fp32 for rescore.
// Zeroes loss.
// ---------------------------------------------------------------------------
__global__ __launch_bounds__(256) void prep(
    const float* __restrict__ z, const float* __restrict__ emb,
    unsigned short* __restrict__ Zpk, unsigned short* __restrict__ Epk,
    float* __restrict__ e2, float* __restrict__ loss) {
    __shared__ float sh[32];
    const int t = threadIdx.x;
    if (blockIdx.x == 0 && t == 0) loss[0] = 0.f;
    if (blockIdx.x < 256) {
        const int n0 = blockIdx.x * 32;
        const int p = t & 31, ks8 = t >> 5;     // 8 k-slabs of 32
        const int n = n0 + p;
        const int b = n >> 10, hw = n & 1023;
        const float* zb = z + (size_t)b * 262144 + hw;
        const int k0 = ks8 * 32;
        float v[32];
        #pragma unroll
        for (int kk = 0; kk < 32; ++kk)
            v[kk] = zb[(size_t)(k0 + kk) * 1024];   // coalesced in p
        const int g = n >> 5;
        #pragma unroll
        for (int i = 0; i < 4; ++i) {               // 4 us8 per 32-k slab
            us8 hv;
            #pragma unroll
            for (int c = 0; c < 8; ++c) hv[c] = f2bf(-2.0f * v[i * 8 + c]);
            const int kabs = k0 + i * 8;
            const int ks = kabs >> 4;
            const int l = (n & 31) + ((kabs >> 3) & 1) * 32;
            *(us8*)(Zpk + ((size_t)(g * 16 + ks) * 64 + l) * 8) = hv;
        }
    } else {
        const int bi = blockIdx.x - 256;            // code group id
        const int j0 = bi * 32;
        const int jj = j0 + (t >> 3), q = t & 7;    // 8 k-slabs of 32
        const float* row = emb + (size_t)jj * D + q * 32;
        float v[32];
        float s = 0.f;
        #pragma unroll
        for (int i = 0; i < 8; ++i) {
            const float4 x = *(const float4*)(row + i * 4);
            v[i * 4] = x.x; v[i * 4 + 1] = x.y; v[i * 4 + 2] = x.z; v[i * 4 + 3] = x.w;
            s += x.x * x.x + x.y * x.y + x.z * x.z + x.w * x.w;
        }
        #pragma unroll
        for (int i = 0; i < 4; ++i) {
            us8 hv;
            #pragma unroll
            for (int c = 0; c < 8; ++c) hv[c] = f2bf(v[i * 8 + c]);
            const int kabs = q * 32 + i * 8;
            const int ks = kabs >> 4;
            const int l = (jj & 31) + ((kabs >> 3) & 1) * 32;
            *(us8*)(Epk + ((size_t)(bi * ECH + ks) * 64 + l) * 8) = hv;
        }
        s += __shfl_xor(s, 1);
        s += __shfl_xor(s, 2);
        s += __shfl_xor(s, 4);
        if (q == 0) { e2[jj] = s; sh[t >> 3] = s; }
        __syncthreads();
        if (t < 64) {   // chunk 16: lane l<32 -> {e2_hi, e2_lo, 0..}; else 0
            us8 hv;
            #pragma unroll
            for (int c = 0; c < 8; ++c) hv[c] = 0;
            if (t < 32) {
                const float vv = sh[t];
                const unsigned short hi = f2bf(vv);
                hv[0] = hi;
                hv[1] = f2bf(vv - bf2f(hi));
            }
            *(us8*)(Epk + ((size_t)bi * ECH + 16) * 512 + t * 8) = hv;
        }
    }
}

// ---------------------------------------------------------------------------
// GEMM + group-min + candidate mask. FINAL (r13 configuration, best measured:
// gemm 80.3 us, FETCH 24.7 MB = compulsory, MfmaUtil 39-40% = 853 TF = the
// plain-HIP 2-barrier-structure ceiling). 15-round design-space verdict:
//  - shape: 64c x 128p @ 2 waves/SIMD optimal (128cx128p/1w: 94us;
//    128cx64p/2w: 90us; 256c-shared/8w: 122us; 128cx32p/4w: 131us).
//  - traffic: E L2-resident via grid (x=strips, y=points); stores [pt][g]
//    coalesced; zero bank conflicts. Traffic changes stopped moving time.
//  - scheduling: depth-2 E parity ring + e2-fold MFMA (chunk 16) are the
//    net-positive refinements; deeper prefetch/preload/unroll spill
//    (r5/r6: FETCH 37->468 MB); grid barriers catastrophic (r12).
// Per (point, 64-code group): tminv[pt][g] min, tmask[pt][g] margin bits.
// ---------------------------------------------------------------------------
__global__ __launch_bounds__(256, 2) void mfma_gemm(
    const unsigned short* __restrict__ Epk, const unsigned short* __restrict__ Zpk,
    float* __restrict__ tminv, u64* __restrict__ tmask) {
    __shared__ unsigned short Zbuf[64 * 512];   // 64 KB (128 points)

    const int tid = threadIdx.x, lane = tid & 63, wid = tid >> 6;
    const int c32 = lane & 31, l5 = lane >> 5;
    const int n0 = (int)blockIdx.y * 128;            // point tile (64)
    const int cs0 = (int)blockIdx.x * (STRIPS * 256); // code strip-col (16)

    // Ones B-fragment for the e2 fold: k-slots 0,1 = 1.0 (l5==0 lanes).
    us8 puu;
    #pragma unroll
    for (int c = 0; c < 8; ++c) puu[c] = 0;
    if (l5 == 0) { puu[0] = 0x3F80; puu[1] = 0x3F80; }
    const bf16x8 pu = (bf16x8)puu;

    #pragma unroll
    for (int ks = 0; ks < 16; ++ks)
        gl_lds16(Zpk + ((size_t)((n0 >> 5) + wid) * 16 + ks) * 512 + lane * 8,
                 Zbuf + (wid * 16 + ks) * 512);
    __syncthreads();   // single drain per block

    for (int s = 0; s < STRIPS; ++s) {
        const int cb = cs0 + s * 256 + wid * 64;   // this wave's 64 codes
        const unsigned short* eb =
            Epk + ((size_t)(cb >> 5) * ECH) * 512 + lane * 8;
        const unsigned short* zb = Zbuf + lane * 8;

        f32x16 acc[2][4];
        const f32x16 z16 = {0.f};
        #pragma unroll
        for (int i = 0; i < 2; ++i)
            #pragma unroll
            for (int j = 0; j < 4; ++j) acc[i][j] = z16;

        // Depth-2 E parity ring: eq0 = even chunks, eq1 = odd chunks.
        bf16x8 eq0a = *(const bf16x8*)(eb);
        bf16x8 eq0b = *(const bf16x8*)(eb + ECH * 512);
        bf16x8 eq1a = *(const bf16x8*)(eb + 512);
        bf16x8 eq1b = *(const bf16x8*)(eb + ECH * 512 + 512);
        bf16x8 pc[4], pn[4];
        #pragma unroll
        for (int j = 0; j < 4; ++j) pc[j] = *(const bf16x8*)(zb + (j * 16) * 512);

        #pragma unroll 4
        for (int ks = 0; ks < 16; ++ks) {
            bf16x8 ef0, ef1;
            if ((ks & 1) == 0) { ef0 = eq0a; ef1 = eq0b; }
            else               { ef0 = eq1a; ef1 = eq1b; }
            if (ks < 15) {      // issue chunk ks+2 (<=16) into the freed slot
                const unsigned short* ep = eb + (ks + 2) * 512;
                if ((ks & 1) == 0) {
                    eq0a = *(const bf16x8*)ep;
                    eq0b = *(const bf16x8*)(ep + ECH * 512);
                } else {
                    eq1a = *(const bf16x8*)ep;
                    eq1b = *(const bf16x8*)(ep + ECH * 512);
                }
                #pragma unroll
                for (int j = 0; j < 4; ++j)
                    pn[j] = *(const bf16x8*)(zb + (j * 16 + ks + 1) * 512);
            }
            acc[0][0] = __builtin_amdgcn_mfma_f32_32x32x16_bf16(ef0, pc[0], acc[0][0], 0, 0, 0);
            acc[0][1] = __builtin_amdgcn_mfma_f32_32x32x16_bf16(ef0, pc[1], acc[0][1], 0, 0, 0);
            acc[0][2] = __builtin_amdgcn_mfma_f32_32x32x16_bf16(ef0, pc[2], acc[0][2], 0, 0, 0);
            acc[0][3] = __builtin_amdgcn_mfma_f32_32x32x16_bf16(ef0, pc[3], acc[0][3], 0, 0, 0);
            acc[1][0] = __builtin_amdgcn_mfma_f32_32x32x16_bf16(ef1, pc[0], acc[1][0], 0, 0, 0);
            acc[1][1] = __builtin_amdgcn_mfma_f32_32x32x16_bf16(ef1, pc[1], acc[1][1], 0, 0, 0);
            acc[1][2] = __builtin_amdgcn_mfma_f32_32x32x16_bf16(ef1, pc[2], acc[1][2], 0, 0, 0);
            acc[1][3] = __builtin_amdgcn_mfma_f32_32x32x16_bf16(ef1, pc[3], acc[1][3], 0, 0, 0);
            if (ks < 15) {
                #pragma unroll
                for (int j = 0; j < 4; ++j) pc[j] = pn[j];
            }
        }
        // e2 fold: chunk 16 arrived in eq0 (loaded at ks=14). acc becomes d~.
        #pragma unroll
        for (int j = 0; j < 4; ++j) {
            acc[0][j] = __builtin_amdgcn_mfma_f32_32x32x16_bf16(eq0a, pu, acc[0][j], 0, 0, 0);
            acc[1][j] = __builtin_amdgcn_mfma_f32_32x32x16_bf16(eq0b, pu, acc[1][j], 0, 0, 0);
        }

        // Epilogue: per point-lane, min over the wave's 64 codes + candidate
        // bitmask (codes within MARGIN of the group min).
        #pragma unroll
        for (int j = 0; j < 4; ++j) {
            float m = acc[0][j][0];
            #pragma unroll
            for (int r = 1; r < 16; ++r) m = fminf(m, acc[0][j][r]);
            #pragma unroll
            for (int r = 0; r < 16; ++r) m = fminf(m, acc[1][j][r]);
            m = fminf(m, __shfl_xor(m, 32));   // fold the two l5 halves
            const float th = m + MARGIN;
            unsigned mk[2];
            #pragma unroll
            for (int i = 0; i < 2; ++i) {
                unsigned mm = 0;
                #pragma unroll
                for (int r = 0; r < 16; ++r) {
                    const int row = (r & 3) + 8 * (r >> 2) + 4 * l5;
                    mm |= (acc[i][j][r] <= th) ? (1u << row) : 0u;
                }
                mk[i] = mm | (unsigned)__shfl_xor((int)mm, 32);
            }
            if (l5 == 0) {
                const size_t pt = (size_t)(n0 + j * 32 + c32);
                tminv[pt * 256 + (cb >> 6)] = m;
                tmask[pt * 256 + (cb >> 6)] = ((u64)mk[1] << 32) | (u64)mk[0];
            }
        }
    }
}

// ---------------------------------------------------------------------------
// Fused rescore + quantize/loss (r13 proven). 256 blocks x 1024 thr; block =
// 32 consecutive points. z tile staged once into LDS smz[32][257] serving
// phase-1 z-rows and phase-2 zv (Zf32 eliminated).
// ---------------------------------------------------------------------------
__global__ __launch_bounds__(1024) void rescore_quant(
    const float* __restrict__ tminv, const u64* __restrict__ tmask,
    const float* __restrict__ emb, const float* __restrict__ e2,
    const float* __restrict__ z, float* __restrict__ out,
    float* __restrict__ out_idx, float* __restrict__ loss) {
    __shared__ float smz[32][257];   // [pt][ch], pad 257
    __shared__ int idx_s[32];
    __shared__ float wsum[16];
    const int tid = threadIdx.x, lane = tid & 63, wd = tid >> 6;
    const int n0 = blockIdx.x * 32;
    const int b = n0 >> 10, hw0 = n0 & 1023;

    // ---- stage z tile: coalesced 128B lines, conflict-free LDS writes ----
    #pragma unroll
    for (int pass = 0; pass < 8; ++pass) {
        const int c = pass * 32 + (tid >> 5);
        const int hw = tid & 31;
        smz[hw][c] = z[(size_t)b * 262144 + (size_t)c * 1024 + hw0 + hw];
    }
    __syncthreads();

    // ---- Phase 1: rescore (each wave: 2 points serially) ----
    #pragma unroll 1
    for (int p = 0; p < 2; ++p) {
        const int lp = wd * 2 + p;
        const int n = n0 + lp;
        const float* zrow = smz[lp];
        const float4 zr = {zrow[lane * 4], zrow[lane * 4 + 1],
                           zrow[lane * 4 + 2], zrow[lane * 4 + 3]};
        const float4 tv = *(const float4*)(tminv + (size_t)n * 256 + lane * 4);

        float m1 = fminf(fminf(tv.x, tv.y), fminf(tv.z, tv.w));
        #pragma unroll
        for (int st = 1; st < 64; st <<= 1) m1 = fminf(m1, __shfl_xor(m1, st));
        const float thresh = m1 + MARGIN;

        u64 best = ~0ull;
        const float tva[4] = {tv.x, tv.y, tv.z, tv.w};
        #pragma unroll
        for (int k = 0; k < 4; ++k) {
            u64 gm = __ballot(tva[k] <= thresh);
            while (gm) {
                const int bit = (int)__builtin_ctzll(gm);
                gm &= gm - 1;
                const int g = bit * 4 + k;                 // 64-code group id
                u64 cm = tmask[(size_t)n * 256 + g];       // uniform broadcast
                while (cm) {
                    const int r = (int)__builtin_ctzll(cm);
                    cm &= cm - 1;
                    const int c = g * 64 + r;
                    const float4 ev = *(const float4*)(emb + (size_t)c * D + lane * 4);
                    float s = zr.x * ev.x + zr.y * ev.y + zr.z * ev.z + zr.w * ev.w;
                    #pragma unroll
                    for (int st = 1; st < 64; st <<= 1) s += __shfl_xor(s, st);
                    const float d = e2[c] - 2.0f * s;
                    unsigned int u = __float_as_uint(d);
                    u = (u & 0x80000000u) ? ~u : (u | 0x80000000u);
                    const u64 key = ((u64)u << 32) | (unsigned int)c;
                    if (key < best) best = key;            // same on all lanes
                }
            }
        }
        if (lane == 0)
            idx_s[lp] = (int)(unsigned int)(best & 0xFFFFFFFFull);
    }
    __syncthreads();

    // ---- Phase 2: gather + z_hat_out + loss (+ coalesced out_idx) ----
    if (tid < 32) {
        const float fv = (float)idx_s[tid];
        #pragma unroll
        for (int sc = 0; sc < 4; ++sc)
            out_idx[b * 4096 + sc * 1024 + hw0 + tid] = fv;
    }
    const int hw_l = tid & 31, cg = tid >> 5;   // cg in [0,32), 8 c each
    const int j = idx_s[hw_l];
    const float* er = emb + (size_t)j * D + cg * 8;
    const float4 q0 = *(const float4*)er;
    const float4 q1 = *(const float4*)(er + 4);
    const float qv[8] = {q0.x, q0.y, q0.z, q0.w, q1.x, q1.y, q1.z, q1.w};
    float e = 0.f;
    #pragma unroll
    for (int cc = 0; cc < 8; ++cc) {
        const int c = cg * 8 + cc;
        const size_t zi = (size_t)b * 262144 + (size_t)c * 1024 + hw0 + hw_l;
        const float zv = smz[hw_l][c];
        const float q = qv[cc];
        const float zh = ((q + q) + q) + q;   // mimic 4-step accumulation
        out[zi] = zv + (zh - zv);
        e += 30.0f * q * q - 20.0f * q * zv + 4.0f * zv * zv;
    }
    #pragma unroll
    for (int off = 32; off > 0; off >>= 1) e += __shfl_down(e, off);
    if (lane == 0) wsum[wd] = e;
    __syncthreads();
    if (tid == 0) {
        float s = 0.f;
        #pragma unroll
        for (int i = 0; i < 16; ++i) s += wsum[i];
        atomicAdd(loss, s * (0.3125f / 2097152.0f));
    }
}

// ---------------------------------------------------------------------------
extern "C" void kernel_launch(void* const* d_in, const int* in_sizes, int n_in,
                              void* d_out, int out_size, void* d_ws, size_t ws_size,
                              hipStream_t stream) {
    const float* z = (const float*)d_in[0];     // [8,256,32,32]
    const float* emb = (const float*)d_in[1];   // [16384,256]
    float* out = (float*)d_out;                 // z_hat_out | loss | total_idx

    // Workspace (~37 MB)
    unsigned short* Zpk = (unsigned short*)d_ws;            // 8192*256 bf16
    unsigned short* Epk = Zpk + (size_t)NPTS * D;           // 512 groups * 17 * 512
    float* e2 = (float*)(Epk + (size_t)(N_E / 32) * ECH * 512);  // 16384 f32
    float* tminv = e2 + N_E;                                // 8192*256 f32 [pt][g]
    u64* tmask = (u64*)(tminv + (size_t)NPTS * 256);        // 8192*256 u64 [pt][g]

    float* loss = out + ZOUT;
    float* out_idx = out + ZOUT + 1;

    prep<<<768, 256, 0, stream>>>(z, emb, Zpk, Epk, e2, loss);
    mfma_gemm<<<dim3(N_E / (256 * STRIPS), NPTS / 128), 256, 0, stream>>>(
        Epk, Zpk, tminv, tmask);
    rescore_quant<<<256, 1024, 0, stream>>>(tminv, tmask, emb, e2, z,
                                            out, out_idx, loss);
}